// Round 1
// baseline (19440.324 us; speedup 1.0000x reference)
//
#include <hip/hip_runtime.h>

static inline int cdiv(int a, int b) { return (a + b - 1) / b; }

#define TILE 64
#define BK 16
#define TPAD 68

// ---------------------------------------------------------------------------
// GEMM: C[m,n] = alpha * sum_k opA(A)[m,k]*opB(B)[k,n] + (Add?Add[m,n]:0) + (addI&&m==n?1:0)
// OPA==0: A is MxK row-major (lda = row stride). OPA==1: A physical KxM; opA[m,k]=A[k*lda+m]
// OPB==0: B is KxN row-major.                    OPB==1: B physical NxK; opB[k,n]=B[n*ldb+k]
// ---------------------------------------------------------------------------
template<int OPA, int OPB>
__global__ __launch_bounds__(256)
void gemm_kernel(int M, int N, int K,
                 const float* A, int lda,
                 const float* B, int ldb,
                 float* C, int ldc,
                 float alpha,
                 const float* Add, int ldadd, int addI)
{
  __shared__ float As[BK][TPAD];
  __shared__ float Bs[BK][TPAD];
  const int tid = (int)threadIdx.x;
  const int tx = tid & 15;
  const int ty = tid >> 4;
  const int bm = (int)blockIdx.y * TILE;
  const int bn = (int)blockIdx.x * TILE;

  float acc[4][4] = {{0.f}};

  for (int k0 = 0; k0 < K; k0 += BK) {
    if (OPA == 0) {
#pragma unroll
      for (int it = 0; it < 4; ++it) {
        int m = (tid >> 4) + 16 * it;
        int kk = tid & 15;
        int gm = bm + m, gk = k0 + kk;
        As[kk][m] = (gm < M && gk < K) ? A[(size_t)gm * lda + gk] : 0.f;
      }
    } else {
#pragma unroll
      for (int it = 0; it < 4; ++it) {
        int m = tid & 63;
        int kk = (tid >> 6) + 4 * it;
        int gm = bm + m, gk = k0 + kk;
        As[kk][m] = (gm < M && gk < K) ? A[(size_t)gk * lda + gm] : 0.f;
      }
    }
    if (OPB == 0) {
#pragma unroll
      for (int it = 0; it < 4; ++it) {
        int nn = tid & 63;
        int kk = (tid >> 6) + 4 * it;
        int gn = bn + nn, gk = k0 + kk;
        Bs[kk][nn] = (gn < N && gk < K) ? B[(size_t)gk * ldb + gn] : 0.f;
      }
    } else {
#pragma unroll
      for (int it = 0; it < 4; ++it) {
        int nn = (tid >> 4) + 16 * it;
        int kk = tid & 15;
        int gn = bn + nn, gk = k0 + kk;
        Bs[kk][nn] = (gn < N && gk < K) ? B[(size_t)gn * ldb + gk] : 0.f;
      }
    }
    __syncthreads();
#pragma unroll
    for (int kk = 0; kk < BK; ++kk) {
      float a4[4], b4[4];
#pragma unroll
      for (int i = 0; i < 4; ++i) a4[i] = As[kk][ty * 4 + i];
#pragma unroll
      for (int j = 0; j < 4; ++j) b4[j] = Bs[kk][tx * 4 + j];
#pragma unroll
      for (int i = 0; i < 4; ++i)
#pragma unroll
        for (int j = 0; j < 4; ++j)
          acc[i][j] = fmaf(a4[i], b4[j], acc[i][j]);
    }
    __syncthreads();
  }
#pragma unroll
  for (int i = 0; i < 4; ++i) {
    int gm = bm + ty * 4 + i;
    if (gm >= M) continue;
#pragma unroll
    for (int j = 0; j < 4; ++j) {
      int gn = bn + tx * 4 + j;
      if (gn >= N) continue;
      float v = alpha * acc[i][j];
      if (Add) v += Add[(size_t)gm * ldadd + gn];
      if (addI && gm == gn) v += 1.f;
      C[(size_t)gm * ldc + gn] = v;
    }
  }
}

static void gemm(hipStream_t st, int opa, int opb, int M, int N, int K,
                 const float* A, int lda, const float* B, int ldb,
                 float* C, int ldc, float alpha,
                 const float* Add, int ldadd, int addI)
{
  dim3 grid(cdiv(N, TILE), cdiv(M, TILE)), blk(256);
  if (opa == 0 && opb == 0)
    gemm_kernel<0,0><<<grid, blk, 0, st>>>(M, N, K, A, lda, B, ldb, C, ldc, alpha, Add, ldadd, addI);
  else if (opa == 0 && opb == 1)
    gemm_kernel<0,1><<<grid, blk, 0, st>>>(M, N, K, A, lda, B, ldb, C, ldc, alpha, Add, ldadd, addI);
  else
    gemm_kernel<1,0><<<grid, blk, 0, st>>>(M, N, K, A, lda, B, ldb, C, ldc, alpha, Add, ldadd, addI);
}

// ---------------------------------------------------------------------------
// Matvec: y[m] = sum_k A[m,k] x[k]   (one 256-thread block per row)
// ---------------------------------------------------------------------------
__global__ __launch_bounds__(256)
void mv_n_kernel(int M, int K, const float* A, int lda, const float* x, float* y)
{
  int m = (int)blockIdx.x;
  if (m >= M) return;
  const float* row = A + (size_t)m * lda;
  float s = 0.f;
  for (int k = (int)threadIdx.x; k < K; k += 256) s += row[k] * x[k];
  __shared__ float red[256];
  red[threadIdx.x] = s;
  __syncthreads();
  for (int off = 128; off > 0; off >>= 1) {
    if ((int)threadIdx.x < off) red[threadIdx.x] += red[threadIdx.x + off];
    __syncthreads();
  }
  if (threadIdx.x == 0) y[m] = red[0];
}

// w[e] = sum_n A[n,e] x[n] + (addv ? addv[e] : 0)   (thread per column)
__global__ __launch_bounds__(256)
void mv_t_kernel(int Nrows, int Ncols, const float* A, int lda,
                 const float* x, const float* addv, float* w)
{
  int e = (int)(blockIdx.x * blockDim.x + threadIdx.x);
  if (e >= Ncols) return;
  float s = 0.f;
  for (int n = 0; n < Nrows; ++n) s += A[(size_t)n * lda + e] * x[n];
  if (addv) s += addv[e];
  w[e] = s;
}

// ---------------------------------------------------------------------------
// elementwise helpers
// ---------------------------------------------------------------------------
__global__ __launch_bounds__(256)
void scale_cols_kernel(long long total, int E, const float* B, const float* sv, float* out)
{
  long long i = (long long)blockIdx.x * blockDim.x + threadIdx.x;
  if (i < total) {
    int e = (int)(i % E);
    out[i] = B[i] * sv[e];
  }
}

__global__ __launch_bounds__(256)
void build_h_kernel(long long total, int E,
                    const float* B, const float* LB, const float* L2B,
                    const float* w0, const float* w1, const float* w2,
                    const float* a, float* H)
{
  long long i = (long long)blockIdx.x * blockDim.x + threadIdx.x;
  if (i < total) {
    int e = (int)(i % E);
    float a1 = a[1], a2 = a[2], a3 = a[3];
    float b = B[i], lb = LB[i], l2b = L2B[i];
    H[i] = w0[e] * (a1 * b + a2 * lb + a3 * l2b)
         + w1[e] * (a2 * b + a3 * lb)
         + w2[e] * (a3 * b);
  }
}

__global__ __launch_bounds__(256)
void poly_resid_kernel(int Nn, const float* a, const float* q,
                       const float* c1, const float* c2, const float* c3,
                       const float* y, float* resid)
{
  int n = (int)(blockIdx.x * blockDim.x + threadIdx.x);
  if (n < Nn)
    resid[n] = y[n] - (a[0] * q[n] + a[1] * c1[n] + a[2] * c2[n] + a[3] * c3[n]);
}

// ---------------------------------------------------------------------------
// index handling
// ---------------------------------------------------------------------------
__global__ __launch_bounds__(256)
void conv_idx_kernel(const void* src, int n, int* dst)
{
  const unsigned* u = (const unsigned*)src;
  bool is64 = (u[1] | u[3] | u[5] | u[7]) == 0u;  // sorted positive ints => odd words 0 iff int64
  int i = (int)(blockIdx.x * blockDim.x + threadIdx.x);
  if (i < n) dst[i] = is64 ? (int)((const long long*)src)[i] : ((const int*)src)[i];
}

__global__ __launch_bounds__(256)
void fill_int_kernel(int* p, int n, int v)
{
  int i = (int)(blockIdx.x * blockDim.x + threadIdx.x);
  if (i < n) p[i] = v;
}

__global__ __launch_bounds__(256)
void scatter_inv_kernel(const int* conn, int K, int* inv)
{
  int i = (int)(blockIdx.x * blockDim.x + threadIdx.x);
  if (i < K) inv[conn[i]] = i;
}

__global__ __launch_bounds__(256)
void mask_s_kernel(int E, const float* s_upd, const int* inv, float* s2, float* outS)
{
  int e = (int)(blockIdx.x * blockDim.x + threadIdx.x);
  if (e < E) {
    float v = (inv[e] >= 0) ? s_upd[e] : 0.f;
    s2[e] = v;
    outS[e] = v;
  }
}

__global__ __launch_bounds__(256)
void gather_cols_kernel(int Nr, int Kc, int E, const float* src, const int* conn, float* dst)
{
  long long i = (long long)blockIdx.x * blockDim.x + threadIdx.x;
  if (i < (long long)Nr * Kc) {
    int n = (int)(i / Kc), c = (int)(i % Kc);
    dst[i] = src[(size_t)n * E + conn[c]];
  }
}

__global__ __launch_bounds__(256)
void gather_scc_kernel(int Kc, int E, const float* Sig, const int* conn, float* Scc)
{
  long long i = (long long)blockIdx.x * blockDim.x + threadIdx.x;
  if (i < (long long)Kc * Kc) {
    int r = (int)(i / Kc), c = (int)(i % Kc);
    Scc[i] = Sig[(size_t)conn[r] * E + conn[c]];
  }
}

__global__ __launch_bounds__(256)
void write_sigma_out_kernel(long long total, int E, const float* Small, int Kc,
                            const int* inv, float* out)
{
  long long i = (long long)blockIdx.x * blockDim.x + threadIdx.x;
  if (i < total) {
    int r = (int)(i / E), c = (int)(i % E);
    int ir = inv[r], ic = inv[c];
    out[i] = (ir >= 0 && ic >= 0) ? Small[(size_t)ir * Kc + ic] : 0.f;
  }
}

// ---------------------------------------------------------------------------
// Cholesky (blocked, NB=128) on SPD matrix, in place, lower factor.
// ---------------------------------------------------------------------------
__global__ __launch_bounds__(128)
void chol_diag_kernel(float* A, int lda, int off, int nb)
{
  __shared__ float T[128][129];
  int tid = (int)threadIdx.x;
  float* Ab = A + (size_t)off * lda + off;
  for (int idx = tid; idx < nb * nb; idx += 128) {
    int r = idx / nb, c = idx % nb;
    T[r][c] = Ab[(size_t)r * lda + c];
  }
  __syncthreads();
  for (int j = 0; j < nb; ++j) {
    float d = sqrtf(T[j][j]);
    __syncthreads();
    if (tid == j) T[j][j] = d;
    if (tid > j && tid < nb) T[tid][j] /= d;
    __syncthreads();
    if (tid > j && tid < nb) {
      float ljr = T[tid][j];
      for (int c = j + 1; c <= tid; ++c)
        T[tid][c] -= ljr * T[c][j];
    }
    __syncthreads();
  }
  for (int idx = tid; idx < nb * nb; idx += 128) {
    int r = idx / nb, c = idx % nb;
    Ab[(size_t)r * lda + c] = T[r][c];
  }
}

// rows below the diagonal block: row <- row * L11^{-T} (forward substitution per row)
__global__ __launch_bounds__(64)
void chol_trsm_kernel(float* A, int lda, int off, int nb, int mrem)
{
  __shared__ float rw[128][64];
  int tid = (int)threadIdx.x;
  int ridx = (int)blockIdx.x * 64 + tid;
  bool act = ridx < mrem;
  const float* Ld = A + (size_t)off * lda + off;  // L11 (read from global, broadcast)
  float* row = A + (size_t)(off + nb + ridx) * lda + off;
  if (act) for (int i = 0; i < nb; ++i) rw[i][tid] = row[i];
  for (int j = 0; j < nb; ++j) {
    float s0 = 0.f, s1 = 0.f, s2 = 0.f, s3 = 0.f;
    const float* Lr = Ld + (size_t)j * lda;
    int i = 0;
    for (; i + 4 <= j; i += 4) {
      s0 += Lr[i]     * rw[i][tid];
      s1 += Lr[i + 1] * rw[i + 1][tid];
      s2 += Lr[i + 2] * rw[i + 2][tid];
      s3 += Lr[i + 3] * rw[i + 3][tid];
    }
    for (; i < j; ++i) s0 += Lr[i] * rw[i][tid];
    float v = (rw[j][tid] - ((s0 + s1) + (s2 + s3))) / Lr[j];
    rw[j][tid] = v;
  }
  if (act) for (int i = 0; i < nb; ++i) row[i] = rw[i][tid];
}

static void cholesky(hipStream_t st, float* S, int n)
{
  const int nb = 128;
  for (int kb = 0; kb < n / nb; ++kb) {
    int off = kb * nb;
    chol_diag_kernel<<<1, 128, 0, st>>>(S, n, off, nb);
    int mrem = n - off - nb;
    if (mrem > 0) {
      chol_trsm_kernel<<<cdiv(mrem, 64), 64, 0, st>>>(S, n, off, nb, mrem);
      float* P = S + (size_t)(off + nb) * n + off;
      float* Ct = S + (size_t)(off + nb) * n + (off + nb);
      gemm(st, 0, 1, mrem, mrem, nb, P, n, P, n, Ct, n, -1.f, Ct, n, 0);
    }
  }
}

// ---------------------------------------------------------------------------
// Triangular solves: Z <- S^{-1} Z  given S = Lc Lc^T (Lc lower, in S)
// ---------------------------------------------------------------------------
__global__ __launch_bounds__(64)
void tri_fwd_kernel(const float* L, int lda, int off, int nb,
                    float* Z, int ldz, int ncols)
{
  __shared__ float zt[128][65];
  int tid = (int)threadIdx.x;
  int c = (int)blockIdx.x * 64 + tid;
  bool act = c < ncols;
  const float* Lb = L + (size_t)off * lda + off;
  float* Zb = Z + (size_t)off * ldz;
  for (int j = 0; j < nb; ++j) {
    float acc = act ? Zb[(size_t)j * ldz + c] : 0.f;
    const float* Lr = Lb + (size_t)j * lda;
    float s0 = 0.f, s1 = 0.f, s2 = 0.f, s3 = 0.f;
    int i = 0;
    for (; i + 4 <= j; i += 4) {
      s0 += Lr[i]     * zt[i][tid];
      s1 += Lr[i + 1] * zt[i + 1][tid];
      s2 += Lr[i + 2] * zt[i + 2][tid];
      s3 += Lr[i + 3] * zt[i + 3][tid];
    }
    for (; i < j; ++i) s0 += Lr[i] * zt[i][tid];
    float v = (acc - ((s0 + s1) + (s2 + s3))) / Lr[j];
    zt[j][tid] = v;
    if (act) Zb[(size_t)j * ldz + c] = v;
  }
}

__global__ __launch_bounds__(64)
void tri_bwd_kernel(const float* L, int lda, int off, int nb,
                    float* Z, int ldz, int ncols)
{
  __shared__ float zt[128][65];
  int tid = (int)threadIdx.x;
  int c = (int)blockIdx.x * 64 + tid;
  bool act = c < ncols;
  float* Zb = Z + (size_t)off * ldz;
  for (int j = nb - 1; j >= 0; --j) {
    float acc = act ? Zb[(size_t)j * ldz + c] : 0.f;
    float s0 = 0.f, s1 = 0.f, s2 = 0.f, s3 = 0.f;
    int i = j + 1;
    for (; i + 4 <= nb; i += 4) {
      s0 += L[(size_t)(off + i) * lda + off + j]     * zt[i][tid];
      s1 += L[(size_t)(off + i + 1) * lda + off + j] * zt[i + 1][tid];
      s2 += L[(size_t)(off + i + 2) * lda + off + j] * zt[i + 2][tid];
      s3 += L[(size_t)(off + i + 3) * lda + off + j] * zt[i + 3][tid];
    }
    for (; i < nb; ++i) s0 += L[(size_t)(off + i) * lda + off + j] * zt[i][tid];
    float v = (acc - ((s0 + s1) + (s2 + s3))) / L[(size_t)(off + j) * lda + off + j];
    zt[j][tid] = v;
    if (act) Zb[(size_t)j * ldz + c] = v;
  }
}

static void trisolve(hipStream_t st, const float* Lc, int n, float* Z, int ldz, int ncols)
{
  const int nb = 128;
  int nblk = n / nb;
  for (int kb = 0; kb < nblk; ++kb) {
    int off = kb * nb;
    tri_fwd_kernel<<<cdiv(ncols, 64), 64, 0, st>>>(Lc, n, off, nb, Z, ldz, ncols);
    int mrem = n - off - nb;
    if (mrem > 0)
      gemm(st, 0, 0, mrem, ncols, nb,
           Lc + (size_t)(off + nb) * n + off, n,
           Z + (size_t)off * ldz, ldz,
           Z + (size_t)(off + nb) * ldz, ldz, -1.f,
           Z + (size_t)(off + nb) * ldz, ldz, 0);
  }
  for (int kb = nblk - 1; kb >= 0; --kb) {
    int off = kb * nb;
    tri_bwd_kernel<<<cdiv(ncols, 64), 64, 0, st>>>(Lc, n, off, nb, Z, ldz, ncols);
    if (off > 0)
      gemm(st, 1, 0, off, ncols, nb,
           Lc + (size_t)off * n, n,      // (L^T)[0:off, block] via OPA=T
           Z + (size_t)off * ldz, ldz,
           Z, ldz, -1.f, Z, ldz, 0);
  }
}

// ---------------------------------------------------------------------------
extern "C" void kernel_launch(void* const* d_in, const int* in_sizes, int n_in,
                              void* d_out, int out_size, void* d_ws, size_t ws_size,
                              hipStream_t stream)
{
  const float* F  = (const float*)d_in[0];
  const float* B  = (const float*)d_in[1];
  const float* V  = (const float*)d_in[2];
  const float* W  = (const float*)d_in[3];
  const float* Sg = (const float*)d_in[4];
  const float* sv = (const float*)d_in[5];
  const float* av = (const float*)d_in[6];
  const float* q  = (const float*)d_in[7];
  const float* y  = (const float*)d_in[8];
  const void*  connRaw = d_in[10];

  const int E  = in_sizes[5];
  const int Nn = in_sizes[7];
  const int Kc = in_sizes[10];

  const size_t EE = (size_t)E * E;
  const size_t NE = (size_t)Nn * E;
  const size_t NN = (size_t)Nn * Nn;
  const size_t NK = (size_t)Nn * Kc;
  const size_t KK = (size_t)Kc * Kc;

  float* ws = (float*)d_ws;
  float* EE_A = ws;
  float* EE_B = EE_A + EE;
  float* NE_1 = EE_B + EE;
  float* NE_2 = NE_1 + NE;
  float* NE_3 = NE_2 + NE;
  float* NN_1 = NE_3 + NE;
  float* vec  = NN_1 + NN;
  float* s1    = vec;            vec += E;
  float* c1    = vec;            vec += Nn;
  float* c2    = vec;            vec += Nn;
  float* c3    = vec;            vec += Nn;
  float* w0    = vec;            vec += E;
  float* w1    = vec;            vec += E;
  float* w2    = vec;            vec += E;
  float* resid = vec;            vec += Nn;
  float* s_upd = vec;            vec += E;
  float* s2    = vec;            vec += E;
  int* conn32  = (int*)vec;
  int* invc    = conn32 + Kc;

  float* outS   = (float*)d_out;   // E
  float* outSig = outS + E;        // E*E; doubles as scratch EE_C until the end
  float* EE_C   = outSig;

  // stage-2 NN-sized scratch carved from dead EE regions
  float* NNa = EE_A;            // H2 (N x K)
  float* NNb = NNa + NK;        // Scc -> T9 -> Sigma_small (K x K)
  float* NNc = NNb + KK;        // T7 -> Y2 (N x K)
  float* NNd = NNc + NK;        // S2 (N x N)
  float* NNe = EE_C;            // ImKH2 (K x K)
  float* NNf = NNe + KK;        // T8 (K x K)

  const long long totNE = (long long)Nn * E;
  const long long totEE = (long long)E * E;

  // ---- stage 1 ----
  mv_n_kernel<<<E, 256, 0, stream>>>(E, E, F, E, sv, s1);                       // s1 = F s
  gemm(stream, 0, 0, E, E, E, F, E, Sg, E, EE_A, E, 1.f, nullptr, 0, 0);        // G1 = F Sigma
  gemm(stream, 0, 1, E, E, E, EE_A, E, F, E, EE_B, E, 1.f, V, E, 0);            // Sigma1 = G1 F^T + V
  scale_cols_kernel<<<cdiv((int)totNE, 256), 256, 0, stream>>>(totNE, E, B, s1, NE_1); // Bs
  gemm(stream, 0, 1, Nn, Nn, E, NE_1, E, B, E, NN_1, Nn, 1.f, nullptr, 0, 0);   // L = Bs B^T
  mv_n_kernel<<<Nn, 256, 0, stream>>>(Nn, Nn, NN_1, Nn, q, c1);
  mv_n_kernel<<<Nn, 256, 0, stream>>>(Nn, Nn, NN_1, Nn, c1, c2);
  mv_n_kernel<<<Nn, 256, 0, stream>>>(Nn, Nn, NN_1, Nn, c2, c3);
  mv_t_kernel<<<cdiv(E, 256), 256, 0, stream>>>(Nn, E, B, E, q,  nullptr, w0);
  mv_t_kernel<<<cdiv(E, 256), 256, 0, stream>>>(Nn, E, B, E, c1, nullptr, w1);
  mv_t_kernel<<<cdiv(E, 256), 256, 0, stream>>>(Nn, E, B, E, c2, nullptr, w2);
  poly_resid_kernel<<<cdiv(Nn, 256), 256, 0, stream>>>(Nn, av, q, c1, c2, c3, y, resid);
  gemm(stream, 0, 0, Nn, E, Nn, NN_1, Nn, B, E, NE_1, E, 1.f, nullptr, 0, 0);   // LB
  gemm(stream, 0, 0, Nn, E, Nn, NN_1, Nn, NE_1, E, NE_2, E, 1.f, nullptr, 0, 0);// L2B
  build_h_kernel<<<cdiv((int)totNE, 256), 256, 0, stream>>>(totNE, E, B, NE_1, NE_2, w0, w1, w2, av, NE_3); // H
  gemm(stream, 0, 0, Nn, E, E, NE_3, E, EE_B, E, NE_1, E, 1.f, nullptr, 0, 0);  // T2 = H Sigma1
  gemm(stream, 0, 1, Nn, Nn, E, NE_1, E, NE_3, E, NN_1, Nn, 1.f, W, Nn, 0);     // S = T2 H^T + W
  cholesky(stream, NN_1, Nn);
  trisolve(stream, NN_1, Nn, NE_1, E, E);                                        // Y = S^{-1} T2 (in place)
  mv_t_kernel<<<cdiv(E, 256), 256, 0, stream>>>(Nn, E, NE_1, E, resid, s1, s_upd); // s_upd = s1 + Y^T resid
  gemm(stream, 1, 0, E, E, Nn, NE_1, E, NE_3, E, EE_A, E, -1.f, nullptr, 0, 1); // ImKH = I - Y^T H
  gemm(stream, 0, 0, E, E, E, EE_A, E, EE_B, E, EE_C, E, 1.f, nullptr, 0, 0);   // T3 = ImKH Sigma1
  gemm(stream, 0, 1, E, E, E, EE_C, E, EE_A, E, EE_B, E, 1.f, nullptr, 0, 0);   // T4 = T3 ImKH^T
  gemm(stream, 1, 0, E, Nn, Nn, NE_1, E, W, Nn, NE_2, Nn, 1.f, nullptr, 0, 0);  // T5 = Y^T W
  gemm(stream, 0, 0, E, E, Nn, NE_2, Nn, NE_1, E, EE_B, E, 1.f, EE_B, E, 0);    // Sigma2 = T5 Y + T4

  // ---- masking / stage 2 ----
  conv_idx_kernel<<<cdiv(Kc, 256), 256, 0, stream>>>(connRaw, Kc, conn32);
  fill_int_kernel<<<cdiv(E, 256), 256, 0, stream>>>(invc, E, -1);
  scatter_inv_kernel<<<cdiv(Kc, 256), 256, 0, stream>>>(conn32, Kc, invc);
  mask_s_kernel<<<cdiv(E, 256), 256, 0, stream>>>(E, s_upd, invc, s2, outS);

  scale_cols_kernel<<<cdiv((int)totNE, 256), 256, 0, stream>>>(totNE, E, B, s2, NE_1); // Bs2
  gemm(stream, 0, 1, Nn, Nn, E, NE_1, E, B, E, NN_1, Nn, 1.f, nullptr, 0, 0);   // L2
  mv_n_kernel<<<Nn, 256, 0, stream>>>(Nn, Nn, NN_1, Nn, q, c1);
  mv_n_kernel<<<Nn, 256, 0, stream>>>(Nn, Nn, NN_1, Nn, c1, c2);
  mv_t_kernel<<<cdiv(E, 256), 256, 0, stream>>>(Nn, E, B, E, q,  nullptr, w0);
  mv_t_kernel<<<cdiv(E, 256), 256, 0, stream>>>(Nn, E, B, E, c1, nullptr, w1);
  mv_t_kernel<<<cdiv(E, 256), 256, 0, stream>>>(Nn, E, B, E, c2, nullptr, w2);
  gemm(stream, 0, 0, Nn, E, Nn, NN_1, Nn, B, E, NE_1, E, 1.f, nullptr, 0, 0);   // L2 B
  gemm(stream, 0, 0, Nn, E, Nn, NN_1, Nn, NE_1, E, NE_2, E, 1.f, nullptr, 0, 0);// L2^2 B
  build_h_kernel<<<cdiv((int)totNE, 256), 256, 0, stream>>>(totNE, E, B, NE_1, NE_2, w0, w1, w2, av, NE_3); // H2full
  gather_cols_kernel<<<cdiv((int)NK, 256), 256, 0, stream>>>(Nn, Kc, E, NE_3, conn32, NNa); // H2
  gather_scc_kernel<<<cdiv((int)KK, 256), 256, 0, stream>>>(Kc, E, EE_B, conn32, NNb);      // Scc
  gemm(stream, 0, 0, Nn, Kc, Kc, NNa, Kc, NNb, Kc, NNc, Kc, 1.f, nullptr, 0, 0);// T7 = H2 Scc
  gemm(stream, 0, 1, Nn, Nn, Kc, NNc, Kc, NNa, Kc, NNd, Nn, 1.f, W, Nn, 0);     // S2 = T7 H2^T + W
  cholesky(stream, NNd, Nn);
  trisolve(stream, NNd, Nn, NNc, Kc, Kc);                                        // Y2 = S2^{-1} T7
  gemm(stream, 1, 0, Kc, Kc, Nn, NNc, Kc, NNa, Kc, NNe, Kc, -1.f, nullptr, 0, 1);// ImKH2 = I - Y2^T H2
  gemm(stream, 0, 0, Kc, Kc, Kc, NNe, Kc, NNb, Kc, NNf, Kc, 1.f, nullptr, 0, 0);// T8 = ImKH2 Scc
  gemm(stream, 0, 1, Kc, Kc, Kc, NNf, Kc, NNe, Kc, NNb, Kc, 1.f, nullptr, 0, 0);// T9 = T8 ImKH2^T
  gemm(stream, 1, 0, Kc, Nn, Nn, NNc, Kc, W, Nn, NNa, Nn, 1.f, nullptr, 0, 0);  // T10 = Y2^T W
  gemm(stream, 0, 0, Kc, Kc, Nn, NNa, Nn, NNc, Kc, NNb, Kc, 1.f, NNb, Kc, 0);   // Small = T10 Y2 + T9

  write_sigma_out_kernel<<<cdiv((int)totEE, 256), 256, 0, stream>>>(totEE, E, NNb, Kc, invc, outSig);

  (void)n_in; (void)out_size; (void)ws_size;
}

// Round 2
// 14435.085 us; speedup vs baseline: 1.3467x; 1.3467x over previous
//
#include <hip/hip_runtime.h>

static inline int cdiv(int a, int b) { return (a + b - 1) / b; }

#define TM 128
#define TN 128
#define GBK 16

// ---------------------------------------------------------------------------
// GEMM: C[m,n] = alpha * sum_k opA(A)[m,k]*opB(B)[k,n] + (Add?Add[m,n]:0) + (addI&&m==n?1:0)
// OPA==0: A is MxK row-major.  OPA==1: A physical KxM; opA[m,k]=A[k*lda+m]
// OPB==0: B is KxN row-major.  OPB==1: B physical NxK; opB[k,n]=B[n*ldb+k]
// REQUIRES: M,N multiples of 128; K multiple of 16; all pointers/lds 16B-aligned.
// ---------------------------------------------------------------------------
template<int OPA, int OPB>
__global__ __launch_bounds__(256)
void gemm_kernel(int M, int N, int K,
                 const float* __restrict__ A, int lda,
                 const float* __restrict__ B, int ldb,
                 float* __restrict__ C, int ldc,
                 float alpha,
                 const float* __restrict__ Add, int ldadd, int addI)
{
  __shared__ float As[GBK][TM];
  __shared__ float Bs[GBK][TN];
  const int tid = (int)threadIdx.x;
  const int tx = tid & 15;
  const int ty = tid >> 4;
  const int bm = (int)blockIdx.y * TM;
  const int bn = (int)blockIdx.x * TN;

  float acc[8][8];
#pragma unroll
  for (int i = 0; i < 8; ++i)
#pragma unroll
    for (int j = 0; j < 8; ++j) acc[i][j] = 0.f;

  for (int k0 = 0; k0 < K; k0 += GBK) {
    if (OPA == 0) {
#pragma unroll
      for (int l = 0; l < 2; ++l) {
        int flat = tid + 256 * l;
        int row = flat >> 2, c = flat & 3;
        const float4 v = *reinterpret_cast<const float4*>(&A[(size_t)(bm + row) * lda + k0 + c * 4]);
        As[c * 4 + 0][row] = v.x; As[c * 4 + 1][row] = v.y;
        As[c * 4 + 2][row] = v.z; As[c * 4 + 3][row] = v.w;
      }
    } else {
#pragma unroll
      for (int l = 0; l < 2; ++l) {
        int flat = tid + 256 * l;
        int kk = flat >> 5, mc = flat & 31;
        const float4 v = *reinterpret_cast<const float4*>(&A[(size_t)(k0 + kk) * lda + bm + mc * 4]);
        *reinterpret_cast<float4*>(&As[kk][mc * 4]) = v;
      }
    }
    if (OPB == 0) {
#pragma unroll
      for (int l = 0; l < 2; ++l) {
        int flat = tid + 256 * l;
        int kk = flat >> 5, nc = flat & 31;
        const float4 v = *reinterpret_cast<const float4*>(&B[(size_t)(k0 + kk) * ldb + bn + nc * 4]);
        *reinterpret_cast<float4*>(&Bs[kk][nc * 4]) = v;
      }
    } else {
#pragma unroll
      for (int l = 0; l < 2; ++l) {
        int flat = tid + 256 * l;
        int row = flat >> 2, c = flat & 3;
        const float4 v = *reinterpret_cast<const float4*>(&B[(size_t)(bn + row) * ldb + k0 + c * 4]);
        Bs[c * 4 + 0][row] = v.x; Bs[c * 4 + 1][row] = v.y;
        Bs[c * 4 + 2][row] = v.z; Bs[c * 4 + 3][row] = v.w;
      }
    }
    __syncthreads();
#pragma unroll
    for (int kk = 0; kk < GBK; ++kk) {
      float a[8], b[8];
      *reinterpret_cast<float4*>(&a[0]) = *reinterpret_cast<const float4*>(&As[kk][ty * 4]);
      *reinterpret_cast<float4*>(&a[4]) = *reinterpret_cast<const float4*>(&As[kk][64 + ty * 4]);
      *reinterpret_cast<float4*>(&b[0]) = *reinterpret_cast<const float4*>(&Bs[kk][tx * 4]);
      *reinterpret_cast<float4*>(&b[4]) = *reinterpret_cast<const float4*>(&Bs[kk][64 + tx * 4]);
#pragma unroll
      for (int i = 0; i < 8; ++i)
#pragma unroll
        for (int j = 0; j < 8; ++j)
          acc[i][j] = fmaf(a[i], b[j], acc[i][j]);
    }
    __syncthreads();
  }
#pragma unroll
  for (int i = 0; i < 8; ++i) {
    int gm = bm + ((i < 4) ? (ty * 4 + i) : (64 + ty * 4 + i - 4));
#pragma unroll
    for (int jh = 0; jh < 2; ++jh) {
      int gn0 = bn + (jh ? (64 + tx * 4) : (tx * 4));
      float vv[4];
#pragma unroll
      for (int j = 0; j < 4; ++j) vv[j] = alpha * acc[i][jh * 4 + j];
      if (Add) {
        const float4 ad = *reinterpret_cast<const float4*>(&Add[(size_t)gm * ldadd + gn0]);
        vv[0] += ad.x; vv[1] += ad.y; vv[2] += ad.z; vv[3] += ad.w;
      }
      if (addI) {
#pragma unroll
        for (int j = 0; j < 4; ++j) if (gm == gn0 + j) vv[j] += 1.f;
      }
      float4 v; v.x = vv[0]; v.y = vv[1]; v.z = vv[2]; v.w = vv[3];
      *reinterpret_cast<float4*>(&C[(size_t)gm * ldc + gn0]) = v;
    }
  }
  (void)M; (void)N;
}

static void gemm(hipStream_t st, int opa, int opb, int M, int N, int K,
                 const float* A, int lda, const float* B, int ldb,
                 float* C, int ldc, float alpha,
                 const float* Add, int ldadd, int addI)
{
  dim3 grid(cdiv(N, TN), cdiv(M, TM)), blk(256);
  if (opa == 0 && opb == 0)
    gemm_kernel<0,0><<<grid, blk, 0, st>>>(M, N, K, A, lda, B, ldb, C, ldc, alpha, Add, ldadd, addI);
  else if (opa == 0 && opb == 1)
    gemm_kernel<0,1><<<grid, blk, 0, st>>>(M, N, K, A, lda, B, ldb, C, ldc, alpha, Add, ldadd, addI);
  else
    gemm_kernel<1,0><<<grid, blk, 0, st>>>(M, N, K, A, lda, B, ldb, C, ldc, alpha, Add, ldadd, addI);
}

// ---------------------------------------------------------------------------
// Matvec helpers
// ---------------------------------------------------------------------------
__global__ __launch_bounds__(256)
void mv_n_kernel(int M, int K, const float* A, int lda, const float* x, float* y)
{
  int m = (int)blockIdx.x;
  if (m >= M) return;
  const float* row = A + (size_t)m * lda;
  float s = 0.f;
  for (int k = (int)threadIdx.x; k < K; k += 256) s += row[k] * x[k];
  __shared__ float red[256];
  red[threadIdx.x] = s;
  __syncthreads();
  for (int off = 128; off > 0; off >>= 1) {
    if ((int)threadIdx.x < off) red[threadIdx.x] += red[threadIdx.x + off];
    __syncthreads();
  }
  if (threadIdx.x == 0) y[m] = red[0];
}

__global__ __launch_bounds__(256)
void mv_t_kernel(int Nrows, int Ncols, const float* A, int lda,
                 const float* x, const float* addv, float* w)
{
  int e = (int)(blockIdx.x * blockDim.x + threadIdx.x);
  if (e >= Ncols) return;
  float s = 0.f;
  for (int n = 0; n < Nrows; ++n) s += A[(size_t)n * lda + e] * x[n];
  if (addv) s += addv[e];
  w[e] = s;
}

// ---------------------------------------------------------------------------
// elementwise helpers
// ---------------------------------------------------------------------------
__global__ __launch_bounds__(256)
void scale_cols_kernel(long long total, int E, const float* B, const float* sv, float* out)
{
  long long i = (long long)blockIdx.x * blockDim.x + threadIdx.x;
  if (i < total) {
    int e = (int)(i % E);
    out[i] = B[i] * sv[e];
  }
}

__global__ __launch_bounds__(256)
void build_h_kernel(long long total, int E,
                    const float* B, const float* LB, const float* L2B,
                    const float* w0, const float* w1, const float* w2,
                    const float* a, float* H)
{
  long long i = (long long)blockIdx.x * blockDim.x + threadIdx.x;
  if (i < total) {
    int e = (int)(i % E);
    float a1 = a[1], a2 = a[2], a3 = a[3];
    float b = B[i], lb = LB[i], l2b = L2B[i];
    H[i] = w0[e] * (a1 * b + a2 * lb + a3 * l2b)
         + w1[e] * (a2 * b + a3 * lb)
         + w2[e] * (a3 * b);
  }
}

__global__ __launch_bounds__(256)
void poly_resid_kernel(int Nn, const float* a, const float* q,
                       const float* c1, const float* c2, const float* c3,
                       const float* y, float* resid)
{
  int n = (int)(blockIdx.x * blockDim.x + threadIdx.x);
  if (n < Nn)
    resid[n] = y[n] - (a[0] * q[n] + a[1] * c1[n] + a[2] * c2[n] + a[3] * c3[n]);
}

__global__ __launch_bounds__(256)
void fzero_kernel(float* p, long long n)
{
  long long i = (long long)blockIdx.x * blockDim.x + threadIdx.x;
  if (i < n) p[i] = 0.f;
}

// ---------------------------------------------------------------------------
// index handling
// ---------------------------------------------------------------------------
__global__ __launch_bounds__(256)
void conv_idx_kernel(const void* src, int n, int* dst)
{
  const unsigned* u = (const unsigned*)src;
  bool is64 = (u[1] | u[3] | u[5] | u[7]) == 0u;
  int i = (int)(blockIdx.x * blockDim.x + threadIdx.x);
  if (i < n) dst[i] = is64 ? (int)((const long long*)src)[i] : ((const int*)src)[i];
}

__global__ __launch_bounds__(256)
void fill_int_kernel(int* p, int n, int v)
{
  int i = (int)(blockIdx.x * blockDim.x + threadIdx.x);
  if (i < n) p[i] = v;
}

__global__ __launch_bounds__(256)
void scatter_inv_kernel(const int* conn, int K, int* inv)
{
  int i = (int)(blockIdx.x * blockDim.x + threadIdx.x);
  if (i < K) inv[conn[i]] = i;
}

__global__ __launch_bounds__(256)
void mask_s_kernel(int E, const float* s_upd, const int* inv, float* s2, float* outS)
{
  int e = (int)(blockIdx.x * blockDim.x + threadIdx.x);
  if (e < E) {
    float v = (inv[e] >= 0) ? s_upd[e] : 0.f;
    s2[e] = v;
    outS[e] = v;
  }
}

__global__ __launch_bounds__(256)
void gather_cols_kernel(int Nr, int Kc, int E, const float* src, const int* conn, float* dst)
{
  long long i = (long long)blockIdx.x * blockDim.x + threadIdx.x;
  if (i < (long long)Nr * Kc) {
    int n = (int)(i / Kc), c = (int)(i % Kc);
    dst[i] = src[(size_t)n * E + conn[c]];
  }
}

__global__ __launch_bounds__(256)
void gather_scc_kernel(int Kc, int E, const float* Sig, const int* conn, float* Scc)
{
  long long i = (long long)blockIdx.x * blockDim.x + threadIdx.x;
  if (i < (long long)Kc * Kc) {
    int r = (int)(i / Kc), c = (int)(i % Kc);
    Scc[i] = Sig[(size_t)conn[r] * E + conn[c]];
  }
}

__global__ __launch_bounds__(256)
void write_sigma_out_kernel(long long total, int E, const float* Small, int Kc,
                            const int* inv, float* out)
{
  long long i = (long long)blockIdx.x * blockDim.x + threadIdx.x;
  if (i < total) {
    int r = (int)(i / E), c = (int)(i % E);
    int ir = inv[r], ic = inv[c];
    out[i] = (ir >= 0 && ic >= 0) ? Small[(size_t)ir * Kc + ic] : 0.f;
  }
}

// ---------------------------------------------------------------------------
// Cholesky leaf: factor 128x128 diag block in place (lower), 256 threads.
// ---------------------------------------------------------------------------
__global__ __launch_bounds__(256)
void chol_diag_kernel(float* A, int lda, int off)
{
  __shared__ float T[128][129];
  const int tid = (int)threadIdx.x;
  const int r = tid & 127;
  const int half = tid >> 7;
  float* Ab = A + (size_t)off * lda + off;
  for (int idx = tid; idx < 128 * 128; idx += 256) {
    int rr = idx >> 7, cc = idx & 127;
    T[rr][cc] = Ab[(size_t)rr * lda + cc];
  }
  __syncthreads();
  for (int j = 0; j < 128; ++j) {
    float d = sqrtf(T[j][j]);
    __syncthreads();
    if (half == 0) {
      if (r == j) T[j][j] = d;
      else if (r > j) T[r][j] /= d;
    }
    __syncthreads();
    if (r > j) {
      float ljr = T[r][j];
      for (int c = j + 1 + half; c <= r; c += 2)
        T[r][c] -= ljr * T[c][j];
    }
    __syncthreads();
  }
  for (int idx = tid; idx < 128 * 128; idx += 256) {
    int rr = idx >> 7, cc = idx & 127;
    Ab[(size_t)rr * lda + cc] = T[rr][cc];
  }
}

// panel rows: row <- row * L11^{-T} (forward substitution per row)
__global__ __launch_bounds__(64)
void chol_trsm_kernel(float* A, int lda, int off, int nb, int mrem)
{
  __shared__ float rw[128][64];
  int tid = (int)threadIdx.x;
  int ridx = (int)blockIdx.x * 64 + tid;
  bool act = ridx < mrem;
  const float* Ld = A + (size_t)off * lda + off;
  float* row = A + (size_t)(off + nb + ridx) * lda + off;
  if (act) for (int i = 0; i < nb; ++i) rw[i][tid] = row[i];
  for (int j = 0; j < nb; ++j) {
    float s0 = 0.f, s1 = 0.f, s2 = 0.f, s3 = 0.f;
    const float* Lr = Ld + (size_t)j * lda;
    int i = 0;
    for (; i + 4 <= j; i += 4) {
      s0 += Lr[i]     * rw[i][tid];
      s1 += Lr[i + 1] * rw[i + 1][tid];
      s2 += Lr[i + 2] * rw[i + 2][tid];
      s3 += Lr[i + 3] * rw[i + 3][tid];
    }
    for (; i < j; ++i) s0 += Lr[i] * rw[i][tid];
    float v = (rw[j][tid] - ((s0 + s1) + (s2 + s3))) / Lr[j];
    rw[j][tid] = v;
  }
  if (act) for (int i = 0; i < nb; ++i) row[i] = rw[i][tid];
}

static void cholesky(hipStream_t st, float* S, int n)
{
  const int nb = 128;
  for (int off = 0; off < n; off += nb) {
    chol_diag_kernel<<<1, 256, 0, st>>>(S, n, off);
    int mrem = n - off - nb;
    if (mrem > 0) {
      chol_trsm_kernel<<<cdiv(mrem, 64), 64, 0, st>>>(S, n, off, nb, mrem);
      float* P = S + (size_t)(off + nb) * n + off;
      float* Ct = S + (size_t)(off + nb) * n + (off + nb);
      gemm(st, 0, 1, mrem, mrem, nb, P, n, P, n, Ct, n, -1.f, Ct, n, 0);
    }
  }
}

// ---------------------------------------------------------------------------
// TRTRI of all 128x128 diagonal blocks in one launch (block b -> diag block b).
// In-place column solve in LDS; writes inverse block (upper zeros) to Out.
// ---------------------------------------------------------------------------
__global__ __launch_bounds__(128)
void trtri_diag_kernel(const float* L, int lda, float* Out, int ldo)
{
  __shared__ float Ls[128][128];
  const int c = (int)threadIdx.x;
  const int off = (int)blockIdx.x * 128;
  const float* Lb = L + (size_t)off * lda + off;
  for (int idx = c; idx < 128 * 128; idx += 128) {
    int rr = idx >> 7, cc = idx & 127;
    Ls[rr][cc] = Lb[(size_t)rr * lda + cc];
  }
  __syncthreads();
  for (int r = 0; r < 128; ++r) {
    float x = 0.f;
    if (c < r) {
      float s = 0.f;
      for (int k = c; k < r; ++k) s += Ls[r][k] * Ls[k][c];
      x = -s / Ls[r][r];
    } else if (c == r) {
      x = 1.f / Ls[r][r];
    }
    __syncthreads();
    if (c <= r) Ls[r][c] = x;
    __syncthreads();
  }
  float* Ob = Out + (size_t)off * ldo + off;
  for (int idx = c; idx < 128 * 128; idx += 128) {
    int rr = idx >> 7, cc = idx & 127;
    Ob[(size_t)rr * ldo + cc] = (cc <= rr) ? Ls[rr][cc] : 0.f;
  }
}

// Build Sinv = L^{-T} L^{-1} from the Cholesky factor (Lf, lower, in S buffer).
// Linv: n*n scratch (zero-filled). TT: >= 512*512 scratch.
static void make_sinv(hipStream_t st, const float* Lf, float* Linv, float* Sinv, float* TT, int n)
{
  long long nn = (long long)n * n;
  fzero_kernel<<<cdiv((int)nn, 256), 256, 0, st>>>(Linv, nn);
  trtri_diag_kernel<<<n / 128, 128, 0, st>>>(Lf, n, Linv, n);
  for (int m = 128; m < n; m <<= 1) {
    for (int o = 0; o + 2 * m <= n; o += 2 * m) {
      // T = L[o+m:o+2m, o:o+m] * invA11
      gemm(st, 0, 0, m, m, m, Lf + (size_t)(o + m) * n + o, n,
           Linv + (size_t)o * n + o, n, TT, m, 1.f, nullptr, 0, 0);
      // Linv[o+m:o+2m, o:o+m] = -invA22 * T
      gemm(st, 0, 0, m, m, m, Linv + (size_t)(o + m) * n + (o + m), n,
           TT, m, Linv + (size_t)(o + m) * n + o, n, -1.f, nullptr, 0, 0);
    }
  }
  gemm(st, 1, 0, n, n, n, Linv, n, Linv, n, Sinv, n, 1.f, nullptr, 0, 0);
}

// ---------------------------------------------------------------------------
extern "C" void kernel_launch(void* const* d_in, const int* in_sizes, int n_in,
                              void* d_out, int out_size, void* d_ws, size_t ws_size,
                              hipStream_t stream)
{
  const float* F  = (const float*)d_in[0];
  const float* B  = (const float*)d_in[1];
  const float* V  = (const float*)d_in[2];
  const float* W  = (const float*)d_in[3];
  const float* Sg = (const float*)d_in[4];
  const float* sv = (const float*)d_in[5];
  const float* av = (const float*)d_in[6];
  const float* q  = (const float*)d_in[7];
  const float* y  = (const float*)d_in[8];
  const void*  connRaw = d_in[10];

  const int E  = in_sizes[5];
  const int Nn = in_sizes[7];
  const int Kc = in_sizes[10];

  const size_t EE = (size_t)E * E;
  const size_t NE = (size_t)Nn * E;
  const size_t NN = (size_t)Nn * Nn;
  const size_t NK = (size_t)Nn * Kc;
  const size_t KK = (size_t)Kc * Kc;

  float* ws = (float*)d_ws;
  float* EE_A = ws;
  float* EE_B = EE_A + EE;
  float* NE_1 = EE_B + EE;
  float* NE_2 = NE_1 + NE;   // also Y / TT / T10 (time-disjoint)
  float* NE_3 = NE_2 + NE;
  float* NN_1 = NE_3 + NE;   // L / S factor
  float* NN_2 = NN_1 + NN;   // Linv
  float* NN_3 = NN_2 + NN;   // Sinv
  float* vec  = NN_3 + NN;
  float* s1    = vec;            vec += E;
  float* c1    = vec;            vec += Nn;
  float* c2    = vec;            vec += Nn;
  float* c3    = vec;            vec += Nn;
  float* w0    = vec;            vec += E;
  float* w1    = vec;            vec += E;
  float* w2    = vec;            vec += E;
  float* resid = vec;            vec += Nn;
  float* s_upd = vec;            vec += E;
  float* s2    = vec;            vec += E;
  int* conn32  = (int*)vec;
  int* invc    = conn32 + Kc;

  float* outS   = (float*)d_out;   // E
  float* outSig = outS + E;        // E*E; scratch until final write
  float* EE_C   = outSig;
  float* TT     = NE_2;            // trtri temp (used before Y/T10 live)

  const long long totNE = (long long)Nn * E;
  const long long totEE = (long long)E * E;

  // ---- stage 1 ----
  mv_n_kernel<<<E, 256, 0, stream>>>(E, E, F, E, sv, s1);                        // s1 = F s
  gemm(stream, 0, 0, E, E, E, F, E, Sg, E, EE_A, E, 1.f, nullptr, 0, 0);         // G1 = F Sigma
  gemm(stream, 0, 1, E, E, E, EE_A, E, F, E, EE_B, E, 1.f, V, E, 0);             // Sigma1 = G1 F^T + V
  scale_cols_kernel<<<cdiv((int)totNE, 256), 256, 0, stream>>>(totNE, E, B, s1, NE_1); // Bs
  gemm(stream, 0, 1, Nn, Nn, E, NE_1, E, B, E, NN_1, Nn, 1.f, nullptr, 0, 0);    // L = Bs B^T
  mv_n_kernel<<<Nn, 256, 0, stream>>>(Nn, Nn, NN_1, Nn, q, c1);
  mv_n_kernel<<<Nn, 256, 0, stream>>>(Nn, Nn, NN_1, Nn, c1, c2);
  mv_n_kernel<<<Nn, 256, 0, stream>>>(Nn, Nn, NN_1, Nn, c2, c3);
  mv_t_kernel<<<cdiv(E, 256), 256, 0, stream>>>(Nn, E, B, E, q,  nullptr, w0);
  mv_t_kernel<<<cdiv(E, 256), 256, 0, stream>>>(Nn, E, B, E, c1, nullptr, w1);
  mv_t_kernel<<<cdiv(E, 256), 256, 0, stream>>>(Nn, E, B, E, c2, nullptr, w2);
  poly_resid_kernel<<<cdiv(Nn, 256), 256, 0, stream>>>(Nn, av, q, c1, c2, c3, y, resid);
  gemm(stream, 0, 0, Nn, E, Nn, NN_1, Nn, B, E, NE_1, E, 1.f, nullptr, 0, 0);    // LB
  gemm(stream, 0, 0, Nn, E, Nn, NN_1, Nn, NE_1, E, NE_2, E, 1.f, nullptr, 0, 0); // L2B
  build_h_kernel<<<cdiv((int)totNE, 256), 256, 0, stream>>>(totNE, E, B, NE_1, NE_2, w0, w1, w2, av, NE_3); // H
  gemm(stream, 0, 0, Nn, E, E, NE_3, E, EE_B, E, NE_1, E, 1.f, nullptr, 0, 0);   // T2 = H Sigma1
  gemm(stream, 0, 1, Nn, Nn, E, NE_1, E, NE_3, E, NN_1, Nn, 1.f, W, Nn, 0);      // S = T2 H^T + W
  cholesky(stream, NN_1, Nn);
  make_sinv(stream, NN_1, NN_2, NN_3, TT, Nn);                                   // Sinv
  gemm(stream, 0, 0, Nn, E, Nn, NN_3, Nn, NE_1, E, NE_2, E, 1.f, nullptr, 0, 0); // Y = Sinv T2
  mv_t_kernel<<<cdiv(E, 256), 256, 0, stream>>>(Nn, E, NE_2, E, resid, s1, s_upd); // s_upd = s1 + Y^T resid
  gemm(stream, 1, 0, E, E, Nn, NE_2, E, NE_3, E, EE_A, E, -1.f, nullptr, 0, 1);  // ImKH = I - Y^T H
  gemm(stream, 0, 0, E, E, E, EE_A, E, EE_B, E, EE_C, E, 1.f, nullptr, 0, 0);    // T3 = ImKH Sigma1
  gemm(stream, 0, 1, E, E, E, EE_C, E, EE_A, E, EE_B, E, 1.f, nullptr, 0, 0);    // T4 = T3 ImKH^T
  gemm(stream, 1, 0, E, Nn, Nn, NE_2, E, W, Nn, NE_1, Nn, 1.f, nullptr, 0, 0);   // T5 = Y^T W
  gemm(stream, 0, 0, E, E, Nn, NE_1, Nn, NE_2, E, EE_B, E, 1.f, EE_B, E, 0);     // Sigma2 = T5 Y + T4

  // ---- masking / stage 2 ----
  conv_idx_kernel<<<cdiv(Kc, 256), 256, 0, stream>>>(connRaw, Kc, conn32);
  fill_int_kernel<<<cdiv(E, 256), 256, 0, stream>>>(invc, E, -1);
  scatter_inv_kernel<<<cdiv(Kc, 256), 256, 0, stream>>>(conn32, Kc, invc);
  mask_s_kernel<<<cdiv(E, 256), 256, 0, stream>>>(E, s_upd, invc, s2, outS);

  scale_cols_kernel<<<cdiv((int)totNE, 256), 256, 0, stream>>>(totNE, E, B, s2, NE_1); // Bs2
  gemm(stream, 0, 1, Nn, Nn, E, NE_1, E, B, E, NN_1, Nn, 1.f, nullptr, 0, 0);    // L2
  mv_n_kernel<<<Nn, 256, 0, stream>>>(Nn, Nn, NN_1, Nn, q, c1);
  mv_n_kernel<<<Nn, 256, 0, stream>>>(Nn, Nn, NN_1, Nn, c1, c2);
  mv_t_kernel<<<cdiv(E, 256), 256, 0, stream>>>(Nn, E, B, E, q,  nullptr, w0);
  mv_t_kernel<<<cdiv(E, 256), 256, 0, stream>>>(Nn, E, B, E, c1, nullptr, w1);
  mv_t_kernel<<<cdiv(E, 256), 256, 0, stream>>>(Nn, E, B, E, c2, nullptr, w2);
  gemm(stream, 0, 0, Nn, E, Nn, NN_1, Nn, B, E, NE_1, E, 1.f, nullptr, 0, 0);    // L2 B
  gemm(stream, 0, 0, Nn, E, Nn, NN_1, Nn, NE_1, E, NE_2, E, 1.f, nullptr, 0, 0); // L2^2 B
  build_h_kernel<<<cdiv((int)totNE, 256), 256, 0, stream>>>(totNE, E, B, NE_1, NE_2, w0, w1, w2, av, NE_3); // H2full
  gather_cols_kernel<<<cdiv((int)NK, 256), 256, 0, stream>>>(Nn, Kc, E, NE_3, conn32, EE_A);        // H2 (Nn x Kc)
  gather_scc_kernel<<<cdiv((int)KK, 256), 256, 0, stream>>>(Kc, E, EE_B, conn32, EE_A + NK);        // Scc (Kc x Kc)
  gemm(stream, 0, 0, Nn, Kc, Kc, EE_A, Kc, EE_A + NK, Kc, EE_B, Kc, 1.f, nullptr, 0, 0); // T7 = H2 Scc
  gemm(stream, 0, 1, Nn, Nn, Kc, EE_B, Kc, EE_A, Kc, NN_1, Nn, 1.f, W, Nn, 0);   // S2 = T7 H2^T + W
  cholesky(stream, NN_1, Nn);
  make_sinv(stream, NN_1, NN_2, NN_3, TT, Nn);
  gemm(stream, 0, 0, Nn, Kc, Nn, NN_3, Nn, EE_B, Kc, NE_1, Kc, 1.f, nullptr, 0, 0);  // Y2 = Sinv2 T7
  gemm(stream, 1, 0, Kc, Kc, Nn, NE_1, Kc, EE_A, Kc, EE_C, Kc, -1.f, nullptr, 0, 1); // ImKH2 = I - Y2^T H2
  gemm(stream, 0, 0, Kc, Kc, Kc, EE_C, Kc, EE_A + NK, Kc, EE_C + KK, Kc, 1.f, nullptr, 0, 0); // T8 = ImKH2 Scc
  gemm(stream, 0, 1, Kc, Kc, Kc, EE_C + KK, Kc, EE_C, Kc, EE_A + NK, Kc, 1.f, nullptr, 0, 0); // T9 = T8 ImKH2^T
  gemm(stream, 1, 0, Kc, Nn, Nn, NE_1, Kc, W, Nn, NE_2, Nn, 1.f, nullptr, 0, 0); // T10 = Y2^T W
  gemm(stream, 0, 0, Kc, Kc, Nn, NE_2, Nn, NE_1, Kc, EE_A + NK, Kc, 1.f, EE_A + NK, Kc, 0); // Small = T10 Y2 + T9

  write_sigma_out_kernel<<<cdiv((int)totEE, 256), 256, 0, stream>>>(totEE, E, EE_A + NK, Kc, invc, outSig);

  (void)n_in; (void)out_size; (void)ws_size;
}